// Round 5
// baseline (12.010 us; speedup 1.0000x reference)
//
#include <hip/hip_runtime.h>
#include <math.h>

#define NPOINTS 32768
#define LOG2E 1.4426950408889634

__device__ __forceinline__ float ex2(float v) { return __builtin_amdgcn_exp2f(v); }

// Ricker cell: c*(2 - r2/s2)*exp(-r2/(2 s2)) = c*((2+BS*dx2) + BS*dy2) * Ex[i]*Ey[j]
// with BS = -1/s2, Ex = 2^(K dx2), Ey = 2^(K dy2), K = -0.5*log2(e)/s2.
// Separability removes the per-cell transcendental.

// Scaling sum (16x16 Gaussian, s2 = (0.9*1.6)^2 exactly, no epsilon),
// rows [R0,R1). Coeff loads are wave-uniform -> s_load.
template<int R0, int R1>
__device__ __forceinline__ float scaling_sep(float x, float y,
                                             const float* __restrict__ c) {
  const float KS = (float)(-0.5 * LOG2E / 2.0736);
  const float SPS = 2.0f / 15.0f;
  float Ey[16];
#pragma unroll
  for (int j = 0; j < 16; ++j) {
    float dy = y - fmaf((float)j, SPS, -1.0f);
    Ey[j] = ex2(KS * (dy * dy));
  }
  float acc = 0.0f;
#pragma unroll
  for (int i = R0; i < R1; ++i) {
    float dx = x - fmaf((float)i, SPS, -1.0f);
    float Exi = ex2(KS * (dx * dx));
    float rd = 0.0f;
#pragma unroll
    for (int j = 0; j < 16; ++j) rd = fmaf(c[i * 16 + j], Ey[j], rd);
    acc = fmaf(Exi, rd, acc);
  }
  return acc;
}

// Level 0: single cell at (-1,-1).
__device__ __forceinline__ float ricker_l0(float x, float y,
                                           const float* __restrict__ c) {
  const double s2d = 0.81 + 1e-8;
  const float K = (float)(-0.5 * LOG2E / s2d);
  const float BS = (float)(-1.0 / s2d);
  float dx = x + 1.0f, dy = y + 1.0f;
  float r2 = fmaf(dy, dy, dx * dx);
  return c[0] * fmaf(BS, r2, 2.0f) * ex2(K * r2);
}

// Full separable ricker level, SZ in {2,4,8}, rows [R0,R1). Uniform loads.
template<int SZ, int R0, int R1>
__device__ __forceinline__ float ricker_full_sep(float x, float y,
                                                 const float* __restrict__ c) {
  const double s2d = (0.9 / SZ) * (0.9 / SZ) + 1e-8;
  const float K = (float)(-0.5 * LOG2E / s2d);
  const float BS = (float)(-1.0 / s2d);
  const float sp = 2.0f / (float)(SZ - 1);
  float Ey[SZ], dy2[SZ];
#pragma unroll
  for (int j = 0; j < SZ; ++j) {
    float dy = y - fmaf((float)j, sp, -1.0f);
    dy2[j] = dy * dy;
    Ey[j] = ex2(K * dy2[j]);
  }
  float acc = 0.0f;
#pragma unroll
  for (int i = R0; i < R1; ++i) {
    float dx = x - fmaf((float)i, sp, -1.0f);
    float dx2 = dx * dx;
    float Exi = ex2(K * dx2);
    float Ai = fmaf(BS, dx2, 2.0f);
#pragma unroll
    for (int j = 0; j < SZ; ++j) {
      float t = fmaf(BS, dy2[j], Ai);
      acc = fmaf(c[i * SZ + j] * t, Exi * Ey[j], acc);
    }
  }
  return acc;
}

// Windowed separable ricker level (SZ = 16/32/64): 4-row x 8-col window.
// Cell spacing = 2.2 sigma; rows fi-1..fi+2 give >= 2-cell (4.4 sigma)
// margin both sides; cols aligned down to 4 (two aligned float4 loads/row)
// give worst-case 2-cell margin. Excluded terms < ~3e-4 each, total < 0.03
// vs threshold 3.62.
template<int SZ>
__device__ __forceinline__ float ricker_win4x8(float x, float y,
                                               const float* __restrict__ c) {
  const double s2d = (0.9 / SZ) * (0.9 / SZ) + 1e-8;
  const float K = (float)(-0.5 * LOG2E / s2d);
  const float BS = (float)(-1.0 / s2d);
  const float sp = 2.0f / (float)(SZ - 1);
  const float inv_sp = (float)(SZ - 1) * 0.5f;
  int fi = (int)floorf((x + 1.0f) * inv_sp);
  int fj = (int)floorf((y + 1.0f) * inv_sp);
  int i0 = min(max(fi - 1, 0), SZ - 4);
  int j0 = min(max((fj - 1) & ~3, 0), SZ - 8);
  float cx0 = fmaf((float)i0, sp, -1.0f);
  float cy0 = fmaf((float)j0, sp, -1.0f);
  float Ey[8], dy2[8];
#pragma unroll
  for (int j = 0; j < 8; ++j) {
    float dy = y - fmaf((float)j, sp, cy0);
    dy2[j] = dy * dy;
    Ey[j] = ex2(K * dy2[j]);
  }
  float acc = 0.0f;
#pragma unroll
  for (int i = 0; i < 4; ++i) {
    float dx = x - fmaf((float)i, sp, cx0);
    float dx2 = dx * dx;
    float Exi = ex2(K * dx2);
    float Ai = fmaf(BS, dx2, 2.0f);
    const float4* rp = (const float4*)(c + (i0 + i) * SZ + j0);  // 16B aligned
    float4 ra = rp[0], rb = rp[1];
    float rv[8] = {ra.x, ra.y, ra.z, ra.w, rb.x, rb.y, rb.z, rb.w};
#pragma unroll
    for (int j = 0; j < 8; ++j) {
      float t = fmaf(BS, dy2[j], Ai);
      acc = fmaf(rv[j] * t, Exi * Ey[j], acc);
    }
  }
  return acc;
}

// One fused kernel: block = 512 threads = 8 waves; wave = work slice,
// lane = point. Partials meet in LDS; wave 0 reduces + softplus + stores.
__global__ __launch_bounds__(512) void wavelet_fused(
    const float2* __restrict__ coords,
    const float* __restrict__ scaling,
    const float* __restrict__ d0, const float* __restrict__ d1,
    const float* __restrict__ d2, const float* __restrict__ d3,
    const float* __restrict__ d4, const float* __restrict__ d5,
    const float* __restrict__ d6,
    float* __restrict__ out) {
  __shared__ float red[8][64];
  int lane = threadIdx.x & 63;
  int slice = __builtin_amdgcn_readfirstlane(threadIdx.x >> 6);
  int p = blockIdx.x * 64 + lane;
  float2 c2 = coords[p];
  float x = c2.x * 0.1f;   // / DOMAIN
  float y = c2.y * 0.1f;
  float acc = 0.0f;

  switch (slice) {
    case 0: acc = scaling_sep<0, 6>(x, y, scaling); break;
    case 1: acc = scaling_sep<6, 11>(x, y, scaling); break;
    case 2: acc = scaling_sep<11, 16>(x, y, scaling); break;
    case 3: acc = ricker_l0(x, y, d0)
                + ricker_full_sep<2, 0, 2>(x, y, d1)
                + ricker_full_sep<8, 0, 4>(x, y, d3); break;
    case 4: acc = ricker_full_sep<4, 0, 4>(x, y, d2)
                + ricker_full_sep<8, 4, 8>(x, y, d3); break;
    case 5: acc = ricker_win4x8<16>(x, y, d4); break;
    case 6: acc = ricker_win4x8<32>(x, y, d5); break;
    default: acc = ricker_win4x8<64>(x, y, d6); break;
  }

  red[slice][lane] = acc;
  __syncthreads();

  if (threadIdx.x < 64) {
    float s = 0.0f;
#pragma unroll
    for (int t = 0; t < 8; ++t) s += red[t][threadIdx.x];
    // numerically-stable softplus (values reach ~181)
    out[p] = fmaxf(s, 0.0f) + log1pf(__expf(-fabsf(s)));
  }
}

extern "C" void kernel_launch(void* const* d_in, const int* in_sizes, int n_in,
                              void* d_out, int out_size, void* d_ws, size_t ws_size,
                              hipStream_t stream) {
  const float2* coords = (const float2*)d_in[0];
  const float* scaling = (const float*)d_in[1];
  const float* d0 = (const float*)d_in[2];
  const float* d1 = (const float*)d_in[3];
  const float* d2 = (const float*)d_in[4];
  const float* d3 = (const float*)d_in[5];
  const float* d4 = (const float*)d_in[6];
  const float* d5 = (const float*)d_in[7];
  const float* d6 = (const float*)d_in[8];

  wavelet_fused<<<NPOINTS / 64, 512, 0, stream>>>(
      coords, scaling, d0, d1, d2, d3, d4, d5, d6, (float*)d_out);
}

// Round 6
// 9.701 us; speedup vs baseline: 1.2380x; 1.2380x over previous
//
#include <hip/hip_runtime.h>
#include <math.h>

#define NPOINTS 32768
#define LOG2E 1.4426950408889634

__device__ __forceinline__ float ex2(float v) { return __builtin_amdgcn_exp2f(v); }

// Ricker cell: c*(2 - r2/s2)*exp(-r2/(2 s2)) = c*((2+BS*dx2) + BS*dy2) * Ex[i]*Ey[j]
// with BS = -1/s2, Ex = 2^(K dx2), Ey = 2^(K dy2), K = -0.5*log2(e)/s2.
// Separability removes the per-cell transcendental.

// Scaling sum (16x16 Gaussian, s2 = (0.9*1.6)^2 exactly, no epsilon),
// rows [R0,R1). Coeff loads are wave-uniform -> s_load.
template<int R0, int R1>
__device__ __forceinline__ float scaling_sep(float x, float y,
                                             const float* __restrict__ c) {
  const float KS = (float)(-0.5 * LOG2E / 2.0736);
  const float SPS = 2.0f / 15.0f;
  float Ey[16];
#pragma unroll
  for (int j = 0; j < 16; ++j) {
    float dy = y - fmaf((float)j, SPS, -1.0f);
    Ey[j] = ex2(KS * (dy * dy));
  }
  float acc = 0.0f;
#pragma unroll
  for (int i = R0; i < R1; ++i) {
    float dx = x - fmaf((float)i, SPS, -1.0f);
    float Exi = ex2(KS * (dx * dx));
    float rd = 0.0f;
#pragma unroll
    for (int j = 0; j < 16; ++j) rd = fmaf(c[i * 16 + j], Ey[j], rd);
    acc = fmaf(Exi, rd, acc);
  }
  return acc;
}

// Level 0: single cell at (-1,-1).
__device__ __forceinline__ float ricker_l0(float x, float y,
                                           const float* __restrict__ c) {
  const double s2d = 0.81 + 1e-8;
  const float K = (float)(-0.5 * LOG2E / s2d);
  const float BS = (float)(-1.0 / s2d);
  float dx = x + 1.0f, dy = y + 1.0f;
  float r2 = fmaf(dy, dy, dx * dx);
  return c[0] * fmaf(BS, r2, 2.0f) * ex2(K * r2);
}

// Full separable ricker level, SZ in {2,4}. Uniform (scalar) coeff loads.
template<int SZ>
__device__ __forceinline__ float ricker_full_sep(float x, float y,
                                                 const float* __restrict__ c) {
  const double s2d = (0.9 / SZ) * (0.9 / SZ) + 1e-8;
  const float K = (float)(-0.5 * LOG2E / s2d);
  const float BS = (float)(-1.0 / s2d);
  const float sp = 2.0f / (float)(SZ - 1);
  float Ey[SZ], dy2[SZ];
#pragma unroll
  for (int j = 0; j < SZ; ++j) {
    float dy = y - fmaf((float)j, sp, -1.0f);
    dy2[j] = dy * dy;
    Ey[j] = ex2(K * dy2[j]);
  }
  float acc = 0.0f;
#pragma unroll
  for (int i = 0; i < SZ; ++i) {
    float dx = x - fmaf((float)i, sp, -1.0f);
    float dx2 = dx * dx;
    float Exi = ex2(K * dx2);
    float Ai = fmaf(BS, dx2, 2.0f);
#pragma unroll
    for (int j = 0; j < SZ; ++j) {
      float t = fmaf(BS, dy2[j], Ai);
      acc = fmaf(c[i * SZ + j] * t, Exi * Ey[j], acc);
    }
  }
  return acc;
}

// Windowed separable ricker level (SZ = 8/16/32/64): 4-row x 8-col window.
// Cell spacing = 2.2-2.5 sigma; rows fi-1..fi+2 give >= 2-cell (>=4.4 sigma)
// margin both sides; cols aligned down to 4 (two aligned float4 loads/row)
// give worst-case 2-cell margin. Excluded terms < ~3e-4 each, total < 0.03
// vs threshold 3.62. For SZ=8 the col window is the whole row (j0 = 0).
template<int SZ>
__device__ __forceinline__ float ricker_win4x8(float x, float y,
                                               const float* __restrict__ c) {
  const double s2d = (0.9 / SZ) * (0.9 / SZ) + 1e-8;
  const float K = (float)(-0.5 * LOG2E / s2d);
  const float BS = (float)(-1.0 / s2d);
  const float sp = 2.0f / (float)(SZ - 1);
  const float inv_sp = (float)(SZ - 1) * 0.5f;
  int fi = (int)floorf((x + 1.0f) * inv_sp);
  int fj = (int)floorf((y + 1.0f) * inv_sp);
  int i0 = min(max(fi - 1, 0), SZ - 4);
  int j0 = min(max((fj - 1) & ~3, 0), SZ - 8);
  float cx0 = fmaf((float)i0, sp, -1.0f);
  float cy0 = fmaf((float)j0, sp, -1.0f);
  float Ey[8], dy2[8];
#pragma unroll
  for (int j = 0; j < 8; ++j) {
    float dy = y - fmaf((float)j, sp, cy0);
    dy2[j] = dy * dy;
    Ey[j] = ex2(K * dy2[j]);
  }
  float acc = 0.0f;
#pragma unroll
  for (int i = 0; i < 4; ++i) {
    float dx = x - fmaf((float)i, sp, cx0);
    float dx2 = dx * dx;
    float Exi = ex2(K * dx2);
    float Ai = fmaf(BS, dx2, 2.0f);
    const float4* rp = (const float4*)(c + (i0 + i) * SZ + j0);  // 16B aligned
    float4 ra = rp[0], rb = rp[1];
    float rv[8] = {ra.x, ra.y, ra.z, ra.w, rb.x, rb.y, rb.z, rb.w};
#pragma unroll
    for (int j = 0; j < 8; ++j) {
      float t = fmaf(BS, dy2[j], Ai);
      acc = fmaf(rv[j] * t, Exi * Ey[j], acc);
    }
  }
  return acc;
}

// One fused kernel: block = 512 threads = 8 waves; wave = work slice,
// lane = point. Partials meet in LDS; wave 0 reduces + softplus + stores.
// Slice balance (approx lane-ops): 206/185/185/130/156/166/166/166.
__global__ __launch_bounds__(512) void wavelet_fused(
    const float2* __restrict__ coords,
    const float* __restrict__ scaling,
    const float* __restrict__ d0, const float* __restrict__ d1,
    const float* __restrict__ d2, const float* __restrict__ d3,
    const float* __restrict__ d4, const float* __restrict__ d5,
    const float* __restrict__ d6,
    float* __restrict__ out) {
  __shared__ float red[8][64];
  int lane = threadIdx.x & 63;
  int slice = __builtin_amdgcn_readfirstlane(threadIdx.x >> 6);
  int p = blockIdx.x * 64 + lane;
  float2 c2 = coords[p];
  float x = c2.x * 0.1f;   // / DOMAIN
  float y = c2.y * 0.1f;
  float acc = 0.0f;

  switch (slice) {
    case 0: acc = scaling_sep<0, 6>(x, y, scaling); break;
    case 1: acc = scaling_sep<6, 11>(x, y, scaling); break;
    case 2: acc = scaling_sep<11, 16>(x, y, scaling); break;
    case 3: acc = ricker_l0(x, y, d0)
                + ricker_full_sep<2>(x, y, d1)
                + ricker_full_sep<4>(x, y, d2); break;
    case 4: acc = ricker_win4x8<8>(x, y, d3); break;
    case 5: acc = ricker_win4x8<16>(x, y, d4); break;
    case 6: acc = ricker_win4x8<32>(x, y, d5); break;
    default: acc = ricker_win4x8<64>(x, y, d6); break;
  }

  red[slice][lane] = acc;
  __syncthreads();

  if (threadIdx.x < 64) {
    float s = 0.0f;
#pragma unroll
    for (int t = 0; t < 8; ++t) s += red[t][threadIdx.x];
    // numerically-stable softplus (values reach ~181)
    out[p] = fmaxf(s, 0.0f) + log1pf(__expf(-fabsf(s)));
  }
}

extern "C" void kernel_launch(void* const* d_in, const int* in_sizes, int n_in,
                              void* d_out, int out_size, void* d_ws, size_t ws_size,
                              hipStream_t stream) {
  const float2* coords = (const float2*)d_in[0];
  const float* scaling = (const float*)d_in[1];
  const float* d0 = (const float*)d_in[2];
  const float* d1 = (const float*)d_in[3];
  const float* d2 = (const float*)d_in[4];
  const float* d3 = (const float*)d_in[5];
  const float* d4 = (const float*)d_in[6];
  const float* d5 = (const float*)d_in[7];
  const float* d6 = (const float*)d_in[8];

  wavelet_fused<<<NPOINTS / 64, 512, 0, stream>>>(
      coords, scaling, d0, d1, d2, d3, d4, d5, d6, (float*)d_out);
}